// Round 6
// baseline (34.472 us; speedup 1.0000x reference)
//
#include <hip/hip_runtime.h>
#include <math.h>

#define D    512
#define NW   4                            // waves per block
#define SWZC(c) ((c) ^ (((c) >> 3) & 7))  // involution on 16B chunk index

typedef __fp16 h2 __attribute__((ext_vector_type(2)));

__device__ __forceinline__ h2 cvt2(float lo, float hi) {
    return __builtin_amdgcn_cvt_pkrtz(lo, hi);
}
// (lo.hi, hi.lo): odd pair (w[2k+1], w[2k+2]) from aligned P[k], P[k+1]
__device__ __forceinline__ h2 oddpair(h2 hi, h2 lo) {
    unsigned u = __builtin_amdgcn_alignbit(__builtin_bit_cast(unsigned, hi),
                                           __builtin_bit_cast(unsigned, lo), 16);
    return __builtin_bit_cast(h2, u);
}
__device__ __forceinline__ h2 bc(unsigned u) { return __builtin_bit_cast(h2, u); }
__device__ __forceinline__ unsigned pk(h2 v) { return __builtin_bit_cast(unsigned, v); }

// ================= K1: gather + add + f16-pack (pure streaming) =============
__global__ __launch_bounds__(256, 4) void pack_kernel(
    const float* __restrict__ ew, const float* __restrict__ eb,
    const float* __restrict__ rw, const float* __restrict__ rb,
    const int* __restrict__ xs, const int* __restrict__ ys,
    const int* __restrict__ rs,
    uint4* __restrict__ wsA, uint4* __restrict__ wsB, uint4* __restrict__ wsR)
{
    const int w    = threadIdx.x >> 6;
    const int l    = threadIdx.x & 63;
    const int item = blockIdx.x * NW + w;

    const int xi = xs[item], yi = ys[item], ri = rs[item];

    // lane l owns f32 [8l, 8l+8) of each row (2 float4 at slots 2l, 2l+1)
    const float4* xw = (const float4*)(ew + (size_t)xi * D);
    const float4* xb = (const float4*)(eb + (size_t)xi * D);
    const float4* yw = (const float4*)(ew + (size_t)yi * D);
    const float4* yb = (const float4*)(eb + (size_t)yi * D);
    const float4* rwp = (const float4*)(rw + (size_t)ri * D);
    const float4* rbp = (const float4*)(rb + (size_t)ri * D);

    float4 a0 = xw[2*l], a1 = xw[2*l+1], a2 = xb[2*l], a3 = xb[2*l+1];
    float4 b0 = yw[2*l], b1 = yw[2*l+1], b2 = yb[2*l], b3 = yb[2*l+1];
    float4 r0 = rwp[2*l], r1 = rwp[2*l+1], r2 = rbp[2*l], r3 = rbp[2*l+1];

    uint4 va, vb, vr;
    va.x = pk(cvt2(a0.x+a2.x, a0.y+a2.y)); va.y = pk(cvt2(a0.z+a2.z, a0.w+a2.w));
    va.z = pk(cvt2(a1.x+a3.x, a1.y+a3.y)); va.w = pk(cvt2(a1.z+a3.z, a1.w+a3.w));
    vb.x = pk(cvt2(b0.x+b2.x, b0.y+b2.y)); vb.y = pk(cvt2(b0.z+b2.z, b0.w+b2.w));
    vb.z = pk(cvt2(b1.x+b3.x, b1.y+b3.y)); vb.w = pk(cvt2(b1.z+b3.z, b1.w+b3.w));
    vr.x = pk(cvt2(r0.x+r2.x, r0.y+r2.y)); vr.y = pk(cvt2(r0.z+r2.z, r0.w+r2.w));
    vr.z = pk(cvt2(r1.x+r3.x, r1.y+r3.y)); vr.w = pk(cvt2(r1.z+r3.z, r1.w+r3.w));

    wsA[(size_t)item * 64 + l]        = va;   // linear
    wsB[(size_t)item * 64 + SWZC(l)]  = vb;   // sigma-image (undoubled)
    wsR[(size_t)item * 64 + l]        = vr;   // linear
}

// ================= K2: sliding-window correlation (f16 fdot2) ===============
__global__ __launch_bounds__(256, 4) void corr_kernel(
    const uint4* __restrict__ wsA, const uint4* __restrict__ wsB,
    const uint4* __restrict__ wsR, float* __restrict__ out)
{
    // per wave: [0..127] bb chunks (sigma-image, doubled), [128..191] a chunks
    __shared__ uint4 smem[NW][192];

    const int w    = threadIdx.x >> 6;
    const int l    = threadIdx.x & 63;
    const int g    = l & 31;              // owns shifts [16g, 16g+16)
    const int jh   = l >> 5;              // j-half: [256jh, 256jh+256)
    const int item = blockIdx.x * NW + w;

    uint4* sB = &smem[w][0];
    uint4* sA = &smem[w][128];

    // ---- stage ws -> LDS (wave-local; compiler handles lgkm/vm ordering) ----
    {
        uint4 tb = wsB[(size_t)item * 64 + l];
        uint4 ta = wsA[(size_t)item * 64 + l];
        sB[l]      = tb;          // LDS[s] holds logical chunk sigma(s)
        sB[64 + l] = tb;          // doubled copy (sigma(c+64)=sigma(c)+64)
        sA[l]      = ta;
    }

    // acc[u] = sum_{j in half} a[j] * bb[512 + j - 16g - u]
    float acc[16];
    #pragma unroll
    for (int u = 0; u < 16; ++u) acc[u] = 0.f;

    // pair-index base B0/2 with B0 = 512 + 256jh - 16g; chunk(k) = c0 + k
    const int c0 = 64 + 32 * jh - 2 * g;
    const int ac0 = 32 * jh;              // a chunk base

    h2 P[16], O[16];                      // rings, slot = (m+8)&15 / (p+8)&15

    // prologue: P slots 0..7 = pairs m=-8..-1 (chunks c0-2, c0-1)
    {
        uint4 t0 = sB[SWZC(c0 - 2)];
        uint4 t1 = sB[SWZC(c0 - 1)];
        P[0]=bc(t0.x); P[1]=bc(t0.y); P[2]=bc(t0.z); P[3]=bc(t0.w);
        P[4]=bc(t1.x); P[5]=bc(t1.y); P[6]=bc(t1.z); P[7]=bc(t1.w);
        #pragma unroll
        for (int p = 0; p < 7; ++p) O[p] = oddpair(P[p+1], P[p]);
    }

    // one step = 8 j's: 1 bb chunk + 1 a chunk + 4 odds + 64 fdot2
#define STEP(s)                                                              \
    do {                                                                     \
        const int k = 4 * kk + (s);                                          \
        const uint4 tb = sB[SWZC(c0 + k)];                                   \
        const uint4 ta = sA[ac0 + k];                                        \
        P[(4*(s)+ 8) & 15] = bc(tb.x);                                       \
        P[(4*(s)+ 9) & 15] = bc(tb.y);                                       \
        P[(4*(s)+10) & 15] = bc(tb.z);                                       \
        P[(4*(s)+11) & 15] = bc(tb.w);                                       \
        const h2 A0 = bc(ta.x), A1 = bc(ta.y), A2 = bc(ta.z), A3 = bc(ta.w); \
        O[(4*(s)+ 7) & 15] = oddpair(P[(4*(s)+ 8) & 15], P[(4*(s)+ 7) & 15]);\
        O[(4*(s)+ 8) & 15] = oddpair(P[(4*(s)+ 9) & 15], P[(4*(s)+ 8) & 15]);\
        O[(4*(s)+ 9) & 15] = oddpair(P[(4*(s)+10) & 15], P[(4*(s)+ 9) & 15]);\
        O[(4*(s)+10) & 15] = oddpair(P[(4*(s)+11) & 15], P[(4*(s)+10) & 15]);\
        _Pragma("unroll")                                                    \
        for (int v = 0; v < 8; ++v) {                                        \
            acc[2*v]   = __builtin_amdgcn_fdot2(A0, P[(4*(s)+0-v+ 8)&15], acc[2*v],   false); \
            acc[2*v+1] = __builtin_amdgcn_fdot2(A0, O[(4*(s)+0-v+ 7)&15], acc[2*v+1], false); \
            acc[2*v]   = __builtin_amdgcn_fdot2(A1, P[(4*(s)+1-v+ 8)&15], acc[2*v],   false); \
            acc[2*v+1] = __builtin_amdgcn_fdot2(A1, O[(4*(s)+1-v+ 7)&15], acc[2*v+1], false); \
            acc[2*v]   = __builtin_amdgcn_fdot2(A2, P[(4*(s)+2-v+ 8)&15], acc[2*v],   false); \
            acc[2*v+1] = __builtin_amdgcn_fdot2(A2, O[(4*(s)+2-v+ 7)&15], acc[2*v+1], false); \
            acc[2*v]   = __builtin_amdgcn_fdot2(A3, P[(4*(s)+3-v+ 8)&15], acc[2*v],   false); \
            acc[2*v+1] = __builtin_amdgcn_fdot2(A3, O[(4*(s)+3-v+ 7)&15], acc[2*v+1], false); \
        }                                                                    \
    } while (0)

    #pragma unroll 1
    for (int kk = 0; kk < 8; ++kk) {      // 32 steps; ring period 4 = unroll
        STEP(0); STEP(1); STEP(2); STEP(3);
    }
#undef STEP

    // ---- epilogue: rel (f16, lane's 16 shifts), reduce, sigmoid ----
    float part = 0.f;
    {
        const uint4 q0 = wsR[(size_t)item * 64 + 2*g];
        const uint4 q1 = wsR[(size_t)item * 64 + 2*g + 1];
        const h2 rh[8] = { bc(q0.x), bc(q0.y), bc(q0.z), bc(q0.w),
                           bc(q1.x), bc(q1.y), bc(q1.z), bc(q1.w) };
        #pragma unroll
        for (int p = 0; p < 8; ++p) {
            part += (float)rh[p][0] * acc[2*p];
            part += (float)rh[p][1] * acc[2*p+1];
        }
    }
    #pragma unroll
    for (int off = 32; off >= 1; off >>= 1) part += __shfl_down(part, off, 64);

    if (l == 0)
        out[item] = 1.0f / (1.0f + expf(-part * (1.0f / (float)D)));
}

extern "C" void kernel_launch(void* const* d_in, const int* in_sizes, int n_in,
                              void* d_out, int out_size, void* d_ws, size_t ws_size,
                              hipStream_t stream)
{
    const float* ew = (const float*)d_in[0];
    const float* eb = (const float*)d_in[1];
    const float* rw = (const float*)d_in[2];
    const float* rb = (const float*)d_in[3];
    const int*   xs = (const int*)d_in[4];
    const int*   ys = (const int*)d_in[5];
    const int*   rs = (const int*)d_in[6];
    float* out = (float*)d_out;

    const int batch = in_sizes[4];                  // 4096
    uint4* wsA = (uint4*)d_ws;                      // [batch][64] 16B chunks
    uint4* wsB = wsA + (size_t)batch * 64;          // [batch][64] sigma-image
    uint4* wsR = wsB + (size_t)batch * 64;          // [batch][64]

    dim3 grid(batch / NW), block(NW * 64);
    pack_kernel<<<grid, block, 0, stream>>>(ew, eb, rw, rb, xs, ys, rs,
                                            wsA, wsB, wsR);
    corr_kernel<<<grid, block, 0, stream>>>(wsA, wsB, wsR, out);
}

// Round 7
// 26.790 us; speedup vs baseline: 1.2867x; 1.2867x over previous
//
#include <hip/hip_runtime.h>
#include <math.h>

#define D    512
#define NW   4                            // waves per block; 1 item per wave
#define SWZC(c) ((c) ^ (((c) >> 3) & 7))  // involution on 16B chunk index

typedef __fp16 h2 __attribute__((ext_vector_type(2)));

__device__ __forceinline__ h2 cvt2(float lo, float hi) {
    return __builtin_amdgcn_cvt_pkrtz(lo, hi);
}
// (lo.hi, hi.lo): odd pair (w[2k+1], w[2k+2]) from aligned P[k], P[k+1]
__device__ __forceinline__ h2 oddpair(h2 hi, h2 lo) {
    unsigned u = __builtin_amdgcn_alignbit(__builtin_bit_cast(unsigned, hi),
                                           __builtin_bit_cast(unsigned, lo), 16);
    return __builtin_bit_cast(h2, u);
}
__device__ __forceinline__ h2 bc(unsigned u) { return __builtin_bit_cast(h2, u); }
__device__ __forceinline__ unsigned pk(h2 v) { return __builtin_bit_cast(unsigned, v); }

__global__ __launch_bounds__(256, 4) void hole_score_kernel(
    const float* __restrict__ ew, const float* __restrict__ eb,
    const float* __restrict__ rw, const float* __restrict__ rb,
    const int* __restrict__ xs, const int* __restrict__ ys,
    const int* __restrict__ rs, float* __restrict__ out)
{
    // per wave: [0..127] bb chunks (sigma-image, doubled), [128..191] a chunks
    __shared__ uint4 smem[NW][192];

    const int w    = threadIdx.x >> 6;
    const int l    = threadIdx.x & 63;
    const int g    = l & 31;              // owns shifts [16g, 16g+16)
    const int jh   = l >> 5;              // j-half: [256jh, 256jh+256)
    const int item = blockIdx.x * NW + w;

    const int xi = xs[item], yi = ys[item], ri = rs[item];

    uint4* sB = &smem[w][0];
    uint4* sA = &smem[w][128];

    // ---- gather (8 coalesced b128), add w+b, cvt to f16, stage (wave-local) ----
    {
        const float4* xw = (const float4*)(ew + (size_t)xi * D);
        const float4* xb = (const float4*)(eb + (size_t)xi * D);
        const float4* yw = (const float4*)(ew + (size_t)yi * D);
        const float4* yb = (const float4*)(eb + (size_t)yi * D);
        // lane l owns f32 [8l, 8l+8) of each row
        float4 a0 = xw[2*l], a1 = xw[2*l+1], a2 = xb[2*l], a3 = xb[2*l+1];
        float4 b0 = yw[2*l], b1 = yw[2*l+1], b2 = yb[2*l], b3 = yb[2*l+1];

        uint4 va, vb;
        va.x = pk(cvt2(a0.x+a2.x, a0.y+a2.y)); va.y = pk(cvt2(a0.z+a2.z, a0.w+a2.w));
        va.z = pk(cvt2(a1.x+a3.x, a1.y+a3.y)); va.w = pk(cvt2(a1.z+a3.z, a1.w+a3.w));
        vb.x = pk(cvt2(b0.x+b2.x, b0.y+b2.y)); vb.y = pk(cvt2(b0.z+b2.z, b0.w+b2.w));
        vb.z = pk(cvt2(b1.x+b3.x, b1.y+b3.y)); vb.w = pk(cvt2(b1.z+b3.z, b1.w+b3.w));

        sA[l] = va;                        // linear
        const int sl = SWZC(l);            // LDS slot s holds chunk sigma(s)
        sB[sl]      = vb;                  // sigma(c+64)=sigma(c)+64
        sB[sl + 64] = vb;                  // doubled copy for circular wrap
    }

    // ---- sliding-window correlation: acc[u] = sum_j a[j]*bb[512+j-16g-u] ----
    float acc[16];
    #pragma unroll
    for (int u = 0; u < 16; ++u) acc[u] = 0.f;

    const int c0  = 64 + 32 * jh - 2 * g;  // bb chunk base (chunk = 8 f16)
    const int ac0 = 32 * jh;               // a chunk base

    h2 P[16], O[16];                       // rings, slot = (pair+8)&15

    {   // prologue: P slots 0..7 = pairs m=-8..-1 (chunks c0-2, c0-1)
        uint4 t0 = sB[SWZC(c0 - 2)];
        uint4 t1 = sB[SWZC(c0 - 1)];
        P[0]=bc(t0.x); P[1]=bc(t0.y); P[2]=bc(t0.z); P[3]=bc(t0.w);
        P[4]=bc(t1.x); P[5]=bc(t1.y); P[6]=bc(t1.z); P[7]=bc(t1.w);
        #pragma unroll
        for (int p = 0; p < 7; ++p) O[p] = oddpair(P[p+1], P[p]);
    }

    // one step = 8 j's: 1 bb chunk + 1 a chunk (broadcast) + 4 odds + 64 fdot2
#define STEP(s)                                                              \
    do {                                                                     \
        const int k = 4 * kk + (s);                                          \
        const uint4 tb = sB[SWZC(c0 + k)];                                   \
        const uint4 ta = sA[ac0 + k];                                        \
        P[(4*(s)+ 8) & 15] = bc(tb.x);                                       \
        P[(4*(s)+ 9) & 15] = bc(tb.y);                                       \
        P[(4*(s)+10) & 15] = bc(tb.z);                                       \
        P[(4*(s)+11) & 15] = bc(tb.w);                                       \
        const h2 A0 = bc(ta.x), A1 = bc(ta.y), A2 = bc(ta.z), A3 = bc(ta.w); \
        O[(4*(s)+ 7) & 15] = oddpair(P[(4*(s)+ 8) & 15], P[(4*(s)+ 7) & 15]);\
        O[(4*(s)+ 8) & 15] = oddpair(P[(4*(s)+ 9) & 15], P[(4*(s)+ 8) & 15]);\
        O[(4*(s)+ 9) & 15] = oddpair(P[(4*(s)+10) & 15], P[(4*(s)+ 9) & 15]);\
        O[(4*(s)+10) & 15] = oddpair(P[(4*(s)+11) & 15], P[(4*(s)+10) & 15]);\
        _Pragma("unroll")                                                    \
        for (int v = 0; v < 8; ++v) {                                        \
            acc[2*v]   = __builtin_amdgcn_fdot2(A0, P[(4*(s)+0-v+ 8)&15], acc[2*v],   false); \
            acc[2*v+1] = __builtin_amdgcn_fdot2(A0, O[(4*(s)+0-v+ 7)&15], acc[2*v+1], false); \
            acc[2*v]   = __builtin_amdgcn_fdot2(A1, P[(4*(s)+1-v+ 8)&15], acc[2*v],   false); \
            acc[2*v+1] = __builtin_amdgcn_fdot2(A1, O[(4*(s)+1-v+ 7)&15], acc[2*v+1], false); \
            acc[2*v]   = __builtin_amdgcn_fdot2(A2, P[(4*(s)+2-v+ 8)&15], acc[2*v],   false); \
            acc[2*v+1] = __builtin_amdgcn_fdot2(A2, O[(4*(s)+2-v+ 7)&15], acc[2*v+1], false); \
            acc[2*v]   = __builtin_amdgcn_fdot2(A3, P[(4*(s)+3-v+ 8)&15], acc[2*v],   false); \
            acc[2*v+1] = __builtin_amdgcn_fdot2(A3, O[(4*(s)+3-v+ 7)&15], acc[2*v+1], false); \
        }                                                                    \
    } while (0)

    #pragma unroll 1
    for (int kk = 0; kk < 8; ++kk) {       // 32 steps; ring period 4 = unroll
        STEP(0); STEP(1); STEP(2); STEP(3);
    }
#undef STEP

    // ---- epilogue: rel dot (f32 from global, L2-hot), reduce, sigmoid ----
    const float4* rwp = (const float4*)(rw + (size_t)ri * D);
    const float4* rbp = (const float4*)(rb + (size_t)ri * D);
    float part = 0.f;
    #pragma unroll
    for (int q = 0; q < 4; ++q) {
        const float4 rA = rwp[(g << 2) + q];
        const float4 rB = rbp[(g << 2) + q];
        part += (rA.x + rB.x) * acc[4*q+0]
              + (rA.y + rB.y) * acc[4*q+1]
              + (rA.z + rB.z) * acc[4*q+2]
              + (rA.w + rB.w) * acc[4*q+3];
    }
    #pragma unroll
    for (int off = 32; off >= 1; off >>= 1) part += __shfl_down(part, off, 64);

    if (l == 0)
        out[item] = 1.0f / (1.0f + expf(-part * (1.0f / (float)D)));
}

extern "C" void kernel_launch(void* const* d_in, const int* in_sizes, int n_in,
                              void* d_out, int out_size, void* d_ws, size_t ws_size,
                              hipStream_t stream)
{
    const float* ew = (const float*)d_in[0];
    const float* eb = (const float*)d_in[1];
    const float* rw = (const float*)d_in[2];
    const float* rb = (const float*)d_in[3];
    const int*   xs = (const int*)d_in[4];
    const int*   ys = (const int*)d_in[5];
    const int*   rs = (const int*)d_in[6];
    float* out = (float*)d_out;

    const int batch = in_sizes[4];          // 4096
    dim3 grid(batch / NW), block(NW * 64);
    hole_score_kernel<<<grid, block, 0, stream>>>(ew, eb, rw, rb, xs, ys, rs, out);
}

// Round 8
// 15.706 us; speedup vs baseline: 2.1948x; 1.7057x over previous
//
#include <hip/hip_runtime.h>
#include <math.h>

#define D    512
#define NW   4                            // waves per block; 1 item per wave

typedef __fp16 h8  __attribute__((ext_vector_type(8)));
typedef __fp16 h2  __attribute__((ext_vector_type(2)));
typedef float  f4_ __attribute__((ext_vector_type(4)));

__device__ __forceinline__ h2 cvt2(float lo, float hi) {
    return __builtin_amdgcn_cvt_pkrtz(lo, hi);
}
__device__ __forceinline__ unsigned pk(h2 v) { return __builtin_bit_cast(unsigned, v); }
__device__ __forceinline__ unsigned ab16(unsigned hi, unsigned lo) {
    return __builtin_amdgcn_alignbit(hi, lo, 16);
}

__global__ __launch_bounds__(256, 4) void hole_mfma_kernel(
    const float* __restrict__ ew, const float* __restrict__ eb,
    const float* __restrict__ rw, const float* __restrict__ rb,
    const int* __restrict__ xs, const int* __restrict__ ys,
    const int* __restrict__ rs, float* __restrict__ out)
{
    // per wave: [0..127] bb doubled, [128..195] a_even (66 used), [196..263] a_odd
    __shared__ uint4 smem[NW][264];

    const int w    = threadIdx.x >> 6;
    const int l    = threadIdx.x & 63;
    const int n    = l & 15;              // MFMA col (shift low bits)
    const int hq   = l >> 4;              // k-group / row-block selector
    const int item = blockIdx.x * NW + w;

    const int xi = xs[item], yi = ys[item], ri = rs[item];

    uint4* sB  = &smem[w][0];
    uint4* sAe = &smem[w][128];
    uint4* sAo = &smem[w][196];

    // ---- rel values early (16 scattered dwords, L2/L3-hot; latency hidden) ----
    const float* rwrow = rw + (size_t)ri * D;
    const float* rbrow = rb + (size_t)ri * D;
    const int ridx = 64 * hq + n;
    float rv[8];
    #pragma unroll
    for (int q = 0; q < 4; ++q) {
        rv[q]     = rwrow[ridx + 16*q]       + rbrow[ridx + 16*q];
        rv[4 + q] = rwrow[ridx + 16*q + 256] + rbrow[ridx + 16*q + 256];
    }

    // ---- gather entity rows (coalesced float4), add w+b, pack f16 ----
    const float4* xw4 = (const float4*)(ew + (size_t)xi * D);
    const float4* xb4 = (const float4*)(eb + (size_t)xi * D);
    const float4* yw4 = (const float4*)(ew + (size_t)yi * D);
    const float4* yb4 = (const float4*)(eb + (size_t)yi * D);
    float4 a0 = xw4[2*l], a1 = xw4[2*l+1], a2 = xb4[2*l], a3 = xb4[2*l+1];
    float4 b0 = yw4[2*l], b1 = yw4[2*l+1], b2 = yb4[2*l], b3 = yb4[2*l+1];

    uint4 va, vb;   // lane's f16 chunk: elements [8l .. 8l+7]
    va.x = pk(cvt2(a0.x+a2.x, a0.y+a2.y)); va.y = pk(cvt2(a0.z+a2.z, a0.w+a2.w));
    va.z = pk(cvt2(a1.x+a3.x, a1.y+a3.y)); va.w = pk(cvt2(a1.z+a3.z, a1.w+a3.w));
    vb.x = pk(cvt2(b0.x+b2.x, b0.y+b2.y)); vb.y = pk(cvt2(b0.z+b2.z, b0.w+b2.w));
    vb.z = pk(cvt2(b1.x+b3.x, b1.y+b3.y)); vb.w = pk(cvt2(b1.z+b3.z, b1.w+b3.w));

    // ---- stage: bb doubled; a even copy; a odd-shifted copy (wave-local) ----
    sB[l]      = vb;
    sB[64 + l] = vb;
    sAe[l]     = va;
    unsigned nx = (unsigned)__shfl((int)va.x, (l + 1) & 63, 64);  // a[8l+8] (circular)
    uint4 vo;   // a_odd chunk l = a[8l+1 .. 8l+8]
    vo.x = ab16(va.y, va.x); vo.y = ab16(va.z, va.y);
    vo.z = ab16(va.w, va.z); vo.w = ab16(nx,   va.w);
    sAo[l] = vo;
    if (l < 2) { sAe[64 + l] = va; sAo[64 + l] = vo; }

    // ---- MFMA main loop ----
    // A[m,k] = bb[512 + k - 16m - 256*tile]; B[k,n] = a[(k+n) mod 512]
    // lane l: m/n = l&15; k = 4*(l>>4) + {0..3} + 16h
    const uint2* sB2 = (const uint2*)sB;                  // 8B units of bb
    const bool oddb = n & 1;
    const bool dsel = (n >> 1) & 1;
    const uint2* aB2 = (const uint2*)(oddb ? sAo : sAe);  // 8B units of a copy

    int ua = 64 + hq - 4 * n;     // unit base: tile1, h0 (tile0 = +64, h1 = +4)
    int ub = hq + (n >> 2);       // unit base: B h0 (h1 = +4)

    f4_ acc0 = {0.f, 0.f, 0.f, 0.f};
    f4_ acc1 = {0.f, 0.f, 0.f, 0.f};

    #pragma unroll
    for (int t = 0; t < 16; ++t) {
        // B-frag: units ub,ub+1 (h0) and ub+4,ub+5 (h1), then 1-dword select
        const uint2 q0 = aB2[ub],     q1 = aB2[ub + 1];
        const uint2 q4 = aB2[ub + 4], q5 = aB2[ub + 5];
        // A-frags: tile1 at ua, ua+4; tile0 at ua+64, ua+68
        const uint2 t10 = sB2[ua],      t11 = sB2[ua + 4];
        const uint2 t00 = sB2[ua + 64], t01 = sB2[ua + 68];

        uint4 bf;
        bf.x = dsel ? q0.y : q0.x;  bf.y = dsel ? q1.x : q0.y;
        bf.z = dsel ? q4.y : q4.x;  bf.w = dsel ? q5.x : q4.y;

        const h8 bfrag  = __builtin_bit_cast(h8, bf);
        const h8 afrag0 = __builtin_bit_cast(h8, make_uint4(t00.x, t00.y, t01.x, t01.y));
        const h8 afrag1 = __builtin_bit_cast(h8, make_uint4(t10.x, t10.y, t11.x, t11.y));

        acc0 = __builtin_amdgcn_mfma_f32_16x16x32_f16(afrag0, bfrag, acc0, 0, 0, 0);
        acc1 = __builtin_amdgcn_mfma_f32_16x16x32_f16(afrag1, bfrag, acc1, 0, 0, 0);

        ua += 8; ub += 8;
    }

    // ---- epilogue: rel dot, full-wave reduce, sigmoid ----
    // acc0[q] = corr_unnorm[64*hq + 16q + n]; acc1[q] = +256
    float part = acc0[0]*rv[0] + acc0[1]*rv[1] + acc0[2]*rv[2] + acc0[3]*rv[3]
               + acc1[0]*rv[4] + acc1[1]*rv[5] + acc1[2]*rv[6] + acc1[3]*rv[7];

    #pragma unroll
    for (int off = 32; off >= 1; off >>= 1) part += __shfl_down(part, off, 64);

    if (l == 0)
        out[item] = 1.0f / (1.0f + expf(-part * (1.0f / (float)D)));
}

extern "C" void kernel_launch(void* const* d_in, const int* in_sizes, int n_in,
                              void* d_out, int out_size, void* d_ws, size_t ws_size,
                              hipStream_t stream)
{
    const float* ew = (const float*)d_in[0];
    const float* eb = (const float*)d_in[1];
    const float* rw = (const float*)d_in[2];
    const float* rb = (const float*)d_in[3];
    const int*   xs = (const int*)d_in[4];
    const int*   ys = (const int*)d_in[5];
    const int*   rs = (const int*)d_in[6];
    float* out = (float*)d_out;

    const int batch = in_sizes[4];          // 4096
    dim3 grid(batch / NW), block(NW * 64);
    hole_mfma_kernel<<<grid, block, 0, stream>>>(ew, eb, rw, rb, xs, ys, rs, out);
}

// Round 9
// 13.546 us; speedup vs baseline: 2.5449x; 1.1595x over previous
//
#include <hip/hip_runtime.h>
#include <math.h>

#define D    512
#define NW   4                             // waves per block; 1 item per wave
#define SWZU(u) ((u) ^ ((((u) >> 4) & 3) << 2))   // bank swizzle on b64 units

typedef __fp16 h8  __attribute__((ext_vector_type(8)));
typedef __fp16 h2  __attribute__((ext_vector_type(2)));
typedef float  f4_ __attribute__((ext_vector_type(4)));

__device__ __forceinline__ h2 cvt2(float lo, float hi) {
    return __builtin_amdgcn_cvt_pkrtz(lo, hi);
}
__device__ __forceinline__ unsigned pk(h2 v) { return __builtin_bit_cast(unsigned, v); }
__device__ __forceinline__ unsigned ab16(unsigned hi, unsigned lo) {
    return __builtin_amdgcn_alignbit(hi, lo, 16);   // (lo.hi16, hi.lo16)
}

__global__ __launch_bounds__(256, 4) void hole_mfma_kernel(
    const float* __restrict__ ew, const float* __restrict__ eb,
    const float* __restrict__ rw, const float* __restrict__ rb,
    const int* __restrict__ xs, const int* __restrict__ ys,
    const int* __restrict__ rs, float* __restrict__ out)
{
    // per wave (uint4 slots): [0..127] bb doubled (unit-swizzled);
    // [128+66c .. 128+66c+65] a-copy shifted by c, c=0..3 (tail = wrap)
    __shared__ uint4 smem[NW][392];

    const int w    = threadIdx.x >> 6;
    const int l    = threadIdx.x & 63;
    const int mn   = l & 15;               // MFMA row m (A) == col n (B)
    const int hq   = l >> 4;               // k-group selector
    const int item = blockIdx.x * NW + w;

    const int xi = xs[item], yi = ys[item], ri = rs[item];

    // ---- rel values early (L2/L3-hot; latency hidden under gather) ----
    const float* rwrow = rw + (size_t)ri * D;
    const float* rbrow = rb + (size_t)ri * D;
    const int ridx = 64 * hq + mn;
    float rv[8];
    #pragma unroll
    for (int q = 0; q < 4; ++q) {
        rv[q]     = rwrow[ridx + 16*q]       + rbrow[ridx + 16*q];
        rv[4 + q] = rwrow[ridx + 16*q + 256] + rbrow[ridx + 16*q + 256];
    }

    // ---- gather entity rows (coalesced float4), add w+b, pack f16 ----
    const float4* xw4 = (const float4*)(ew + (size_t)xi * D);
    const float4* xb4 = (const float4*)(eb + (size_t)xi * D);
    const float4* yw4 = (const float4*)(ew + (size_t)yi * D);
    const float4* yb4 = (const float4*)(eb + (size_t)yi * D);
    float4 a0 = xw4[2*l], a1 = xw4[2*l+1], a2 = xb4[2*l], a3 = xb4[2*l+1];
    float4 b0 = yw4[2*l], b1 = yw4[2*l+1], b2 = yb4[2*l], b3 = yb4[2*l+1];

    uint4 va, vb;   // lane's f16 chunk: elements [8l .. 8l+7]
    va.x = pk(cvt2(a0.x+a2.x, a0.y+a2.y)); va.y = pk(cvt2(a0.z+a2.z, a0.w+a2.w));
    va.z = pk(cvt2(a1.x+a3.x, a1.y+a3.y)); va.w = pk(cvt2(a1.z+a3.z, a1.w+a3.w));
    vb.x = pk(cvt2(b0.x+b2.x, b0.y+b2.y)); vb.y = pk(cvt2(b0.z+b2.z, b0.w+b2.w));
    vb.z = pk(cvt2(b1.x+b3.x, b1.y+b3.y)); vb.w = pk(cvt2(b1.z+b3.z, b1.w+b3.w));

    uint4* S = smem[w];

    // ---- stage bb doubled, unit-swizzled (uint4 slot = SWZU(2l)>>1) ----
    {
        const int s0 = SWZU(2*l) >> 1;     // SWZU preserves pair adjacency
        S[s0]      = vb;                   // SWZU(u+128) = SWZU(u)+128
        S[s0 + 64] = vb;
    }
    // ---- stage 4 shifted a-copies: copy_c[i] = a[(i+c) mod 512] ----
    {
        const unsigned nx1 = (unsigned)__shfl((int)va.x, (l + 1) & 63, 64); // a[8l+8,9]
        const unsigned nx2 = (unsigned)__shfl((int)va.y, (l + 1) & 63, 64); // a[8l+10,11]
        uint4 c1, c2, c3;
        c1.x = ab16(va.y, va.x); c1.y = ab16(va.z, va.y);
        c1.z = ab16(va.w, va.z); c1.w = ab16(nx1,  va.w);
        c2.x = va.y; c2.y = va.z; c2.z = va.w; c2.w = nx1;
        c3.x = ab16(va.z, va.y); c3.y = ab16(va.w, va.z);
        c3.z = ab16(nx1,  va.w); c3.w = ab16(nx2,  nx1);
        S[128 + l]           = va;
        S[128 + 66 + l]      = c1;
        S[128 + 132 + l]     = c2;
        S[128 + 198 + l]     = c3;
        if (l < 2) {                       // wrap tails (units 128..131 of each copy)
            S[128 + 64 + l]        = va;
            S[128 + 66 + 64 + l]   = c1;
            S[128 + 132 + 64 + l]  = c2;
            S[128 + 198 + 64 + l]  = c3;
        }
    }

    // ---- MFMA main loop: 16 iters of 16x16x32, two 16x16 shift-tiles ----
    // A[m,k] = bb[512 + k - 16m - 256*tile]; B[k,n] = a[(k+n) mod 512]
    // lane: m = n = mn, k = 4hq + {0..3} + 16h + 32t
    const uint2* W = (const uint2*)S;      // b64 units; bb = [0..255]
    int lu = 128 + hq - 4 * mn;            // tile0 logical unit (h0); tile1 = -64
    int ub = 256 + 132 * (mn & 3) + hq + (mn >> 2);   // a-copy b64 base

    f4_ acc0 = {0.f, 0.f, 0.f, 0.f};
    f4_ acc1 = {0.f, 0.f, 0.f, 0.f};

    #pragma unroll
    for (int t = 0; t < 16; ++t) {
        const int s0 = SWZU(lu), s1 = SWZU(lu + 4);
        const uint2 p00 = W[s0],      p01 = W[s1];        // tile0 h0,h1
        const uint2 p10 = W[s0 - 64], p11 = W[s1 - 64];   // tile1 h0,h1
        const uint2 q0  = W[ub],      q1  = W[ub + 4];    // B h0,h1

        const h8 af0 = __builtin_bit_cast(h8, make_uint4(p00.x, p00.y, p01.x, p01.y));
        const h8 af1 = __builtin_bit_cast(h8, make_uint4(p10.x, p10.y, p11.x, p11.y));
        const h8 bf  = __builtin_bit_cast(h8, make_uint4(q0.x,  q0.y,  q1.x,  q1.y));

        acc0 = __builtin_amdgcn_mfma_f32_16x16x32_f16(af0, bf, acc0, 0, 0, 0);
        acc1 = __builtin_amdgcn_mfma_f32_16x16x32_f16(af1, bf, acc1, 0, 0, 0);

        lu += 8; ub += 8;
    }

    // ---- epilogue: rel dot, full-wave reduce, sigmoid ----
    // acc0[q] = corr_unnorm[64hq + 16q + mn]; acc1[q] = +256
    float part = acc0[0]*rv[0] + acc0[1]*rv[1] + acc0[2]*rv[2] + acc0[3]*rv[3]
               + acc1[0]*rv[4] + acc1[1]*rv[5] + acc1[2]*rv[6] + acc1[3]*rv[7];

    #pragma unroll
    for (int off = 32; off >= 1; off >>= 1) part += __shfl_down(part, off, 64);

    if (l == 0)
        out[item] = 1.0f / (1.0f + expf(-part * (1.0f / (float)D)));
}

extern "C" void kernel_launch(void* const* d_in, const int* in_sizes, int n_in,
                              void* d_out, int out_size, void* d_ws, size_t ws_size,
                              hipStream_t stream)
{
    const float* ew = (const float*)d_in[0];
    const float* eb = (const float*)d_in[1];
    const float* rw = (const float*)d_in[2];
    const float* rb = (const float*)d_in[3];
    const int*   xs = (const int*)d_in[4];
    const int*   ys = (const int*)d_in[5];
    const int*   rs = (const int*)d_in[6];
    float* out = (float*)d_out;

    const int batch = in_sizes[4];          // 4096
    dim3 grid(batch / NW), block(NW * 64);
    hole_mfma_kernel<<<grid, block, 0, stream>>>(ew, eb, rw, rb, xs, ys, rs, out);
}